// Round 1
// baseline (68.607 us; speedup 1.0000x reference)
//
#include <hip/hip_runtime.h>
#include <math.h>

#define TT   256
#define TM1  255
#define QD   9
#define KD   5
#define NH   3
#define DD   15   // NH*KD
#define HID  75   // 5*DD

__device__ __forceinline__ float fast_tanh(float x) {
    // tanh(x) = 1 - 2/(exp(2x)+1); saturates correctly for large |x|
    float e = __expf(2.0f * x);
    return 1.0f - 2.0f / (e + 1.0f);
}

__global__ __launch_bounds__(256)
void fused_block_kernel(const float* __restrict__ state,   // (32,256,7)
                        const float* __restrict__ action,  // (32,256,2)
                        const float* __restrict__ Wk,      // (15,5)
                        const float* __restrict__ Wq,      // (15,9)
                        const float* __restrict__ Wv,      // (15,5)
                        const float* __restrict__ att_bias,// (5)
                        const float* __restrict__ Wscore,  // (1,5)
                        const float* __restrict__ bscore,  // (1)
                        const float* __restrict__ g1,
                        const float* __restrict__ beta1,
                        const float* __restrict__ W1,      // (75,15)
                        const float* __restrict__ bff1,    // (75)
                        const float* __restrict__ W2,      // (15,75)
                        const float* __restrict__ bff2,    // (15)
                        const float* __restrict__ g2,
                        const float* __restrict__ beta2,
                        float* __restrict__ out)           // (32,256,15)
{
    const int blk = blockIdx.x;        // b*256 + i
    const int b   = blk >> 8;
    const int qi  = blk & 255;
    const int m   = threadIdx.x;       // neighbor slot (0..254 valid)
    const int lane = m & 63;
    const int wave = m >> 6;

    __shared__ float s_wk[DD*KD], s_wv[DD*KD];
    __shared__ float s_bias[KD], s_wsc[KD];
    __shared__ float s_b0;
    __shared__ float s_q[DD];
    __shared__ float s_red[4][NH+DD];
    __shared__ float s_fin[NH+DD];
    __shared__ float s_x[DD];
    __shared__ float s_h[HID];
    __shared__ float s_x2[DD];
    __shared__ float s_mv[2];

    // ---- stage small weights / compute query projection (disjoint thread ranges)
    if (m < DD*KD)                       s_wk[m]       = Wk[m];
    else if (m < 2*DD*KD)                s_wv[m-DD*KD] = Wv[m-DD*KD];
    else if (m >= 160 && m < 160+KD)     s_bias[m-160] = att_bias[m-160];
    else if (m >= 170 && m < 170+KD)     s_wsc[m-170]  = Wscore[m-170];
    else if (m == 180)                   s_b0          = bscore[0];
    if (m >= 192 && m < 192+DD) {
        const int d = m - 192;
        const float* st = state + ((size_t)b*TT + qi)*7;
        float acc = 0.0f;
        #pragma unroll
        for (int k = 0; k < 7; k++) acc += Wq[d*QD+k] * st[k];
        acc += Wq[d*QD+7] * action[((size_t)b*TT+qi)*2 + 0];
        acc += Wq[d*QD+8] * action[((size_t)b*TT+qi)*2 + 1];
        s_q[d] = acc;
    }
    __syncthreads();

    // ---- per-pair phase
    float red[NH+DD];
    #pragma unroll
    for (int n = 0; n < NH+DD; n++) red[n] = 0.0f;

    const bool valid = (m < TM1);
    if (valid) {
        const int jj = m + (m >= qi ? 1 : 0);
        const float* sti = state + ((size_t)b*TT + qi)*7;
        const float* stj = state + ((size_t)b*TT + jj)*7;
        const float d0 = stj[0]-sti[0];
        const float d1 = stj[1]-sti[1];
        const float d2 = stj[2]-sti[2];
        const float d3 = stj[3]-sti[3];
        // angle of the NEIGHBOR (broadcast in ref indexes axis 2 = j)
        const float ang = 1.5707963267948966f - stj[6];
        float sn, cs;
        __sincosf(ang, &sn, &cs);
        const float xr0 = d0*cs - d1*sn;
        const float yr0 = d0*sn + d1*cs;
        const float xr1 = d2*cs - d3*sn;
        const float yr1 = d2*sn + d3*cs;
        const float r    = sqrtf(xr0*xr0 + yr0*yr0);
        const float rinv = 1.0f / r;
        const float rt   = 1.0f / (1.0f + __expf(5.0f*r - 2.0f)); // sigmoid(1-5(r-0.2))
        const float kv[KD] = {xr0*rinv, yr0*rinv, xr1, yr1, rt};

        float vv[DD];
        float p[NH];
        #pragma unroll
        for (int h = 0; h < NH; h++) {
            float sc = s_b0;
            #pragma unroll
            for (int kk = 0; kk < KD; kk++) {
                const int d = h*KD + kk;
                float key = 0.0f, val = 0.0f;
                #pragma unroll
                for (int cc = 0; cc < KD; cc++) {
                    key += s_wk[d*KD+cc] * kv[cc];
                    val += s_wv[d*KD+cc] * kv[cc];
                }
                vv[d] = val;
                sc += fast_tanh(key + s_q[d] + s_bias[kk]) * s_wsc[kk];
            }
            // |sc| <= ~2.7 (tanh in [-1,1], |Wscore|<=0.447) -> safe without max-sub
            p[h] = __expf(sc);
        }
        #pragma unroll
        for (int h = 0; h < NH; h++) {
            red[h] = p[h];
            #pragma unroll
            for (int kk = 0; kk < KD; kk++)
                red[NH + h*KD + kk] = p[h] * vv[h*KD + kk];
        }
    }

    // ---- block reduction: 3 softmax denoms + 15 weighted value sums
    #pragma unroll
    for (int off = 32; off >= 1; off >>= 1) {
        #pragma unroll
        for (int n = 0; n < NH+DD; n++)
            red[n] += __shfl_xor(red[n], off);
    }
    if (lane == 0) {
        #pragma unroll
        for (int n = 0; n < NH+DD; n++) s_red[wave][n] = red[n];
    }
    __syncthreads();
    if (m < NH+DD)
        s_fin[m] = s_red[0][m] + s_red[1][m] + s_red[2][m] + s_red[3][m];
    __syncthreads();

    // ---- epilogue: softmax-normalize, LN1, MLP, residual, LN2
    if (m < DD)
        s_x[m] = s_fin[NH + m] / s_fin[m / KD];
    __syncthreads();
    if (m == 0) {
        float mu = 0.0f;
        #pragma unroll
        for (int d = 0; d < DD; d++) mu += s_x[d];
        mu *= (1.0f/DD);
        float var = 0.0f;
        #pragma unroll
        for (int d = 0; d < DD; d++) { float tv = s_x[d]-mu; var += tv*tv; }
        var *= (1.0f/DD);
        s_mv[0] = mu; s_mv[1] = rsqrtf(var + 1e-5f);
    }
    __syncthreads();
    if (m < DD)
        s_x[m] = (s_x[m] - s_mv[0]) * s_mv[1] * g1[m] + beta1[m];
    __syncthreads();
    if (m < HID) {
        float acc = bff1[m];
        #pragma unroll
        for (int k = 0; k < DD; k++) acc += W1[m*DD+k] * s_x[k];
        s_h[m] = fmaxf(acc, 0.0f);
    }
    __syncthreads();
    if (m < DD) {
        float acc = bff2[m];
        #pragma unroll
        for (int j = 0; j < HID; j++) acc += W2[m*HID+j] * s_h[j];
        s_x2[m] = s_x[m] + acc;   // residual uses post-LN1 x
    }
    __syncthreads();
    if (m == 0) {
        float mu = 0.0f;
        #pragma unroll
        for (int d = 0; d < DD; d++) mu += s_x2[d];
        mu *= (1.0f/DD);
        float var = 0.0f;
        #pragma unroll
        for (int d = 0; d < DD; d++) { float tv = s_x2[d]-mu; var += tv*tv; }
        var *= (1.0f/DD);
        s_mv[0] = mu; s_mv[1] = rsqrtf(var + 1e-5f);
    }
    __syncthreads();
    if (m < DD)
        out[(size_t)blk*DD + m] = (s_x2[m] - s_mv[0]) * s_mv[1] * g2[m] + beta2[m];
}

extern "C" void kernel_launch(void* const* d_in, const int* in_sizes, int n_in,
                              void* d_out, int out_size, void* d_ws, size_t ws_size,
                              hipStream_t stream) {
    const float* state    = (const float*)d_in[0];
    const float* action   = (const float*)d_in[1];
    const float* Wk       = (const float*)d_in[2];
    const float* Wq       = (const float*)d_in[3];
    const float* Wv       = (const float*)d_in[4];
    const float* att_bias = (const float*)d_in[5];
    const float* Wscore   = (const float*)d_in[6];
    const float* bscore   = (const float*)d_in[7];
    const float* g1       = (const float*)d_in[8];
    const float* beta1    = (const float*)d_in[9];
    const float* W1       = (const float*)d_in[10];
    const float* bff1     = (const float*)d_in[11];
    const float* W2       = (const float*)d_in[12];
    const float* bff2     = (const float*)d_in[13];
    const float* g2       = (const float*)d_in[14];
    const float* beta2    = (const float*)d_in[15];
    float* out = (float*)d_out;

    dim3 grid(32 * 256);
    dim3 block(256);
    fused_block_kernel<<<grid, block, 0, stream>>>(
        state, action, Wk, Wq, Wv, att_bias, Wscore, bscore,
        g1, beta1, W1, bff1, W2, bff2, g2, beta2, out);
}

// Round 2
// 35.441 us; speedup vs baseline: 1.9358x; 1.9358x over previous
//
#include <hip/hip_runtime.h>
#include <math.h>

#define TT   256
#define TM1  255
#define QD   9
#define KD   5
#define NH   3
#define DD   15   // NH*KD
#define HID  75   // 5*DD
#define NR   18   // NH + DD reduce values

__device__ __forceinline__ float fast_rcp(float x) {
    return __builtin_amdgcn_rcpf(x);   // v_rcp_f32, ~1 ulp
}

__device__ __forceinline__ float fast_tanh(float x) {
    // tanh(x) = 1 - 2/(exp(2x)+1); saturates correctly for large |x|
    float e = __expf(2.0f * x);
    return fmaf(-2.0f, fast_rcp(e + 1.0f), 1.0f);
}

template<int CTRL>
__device__ __forceinline__ float dpp_add(float x) {
    int y = __builtin_amdgcn_update_dpp(0, __float_as_int(x), CTRL, 0xf, 0xf, true);
    return x + __int_as_float(y);
}

// full-rate VALU wave64 sum; result valid in lane 63
__device__ __forceinline__ float wave_sum63(float x) {
    x = dpp_add<0x111>(x);  // row_shr:1
    x = dpp_add<0x112>(x);  // row_shr:2
    x = dpp_add<0x114>(x);  // row_shr:4
    x = dpp_add<0x118>(x);  // row_shr:8
    x = dpp_add<0x142>(x);  // row_bcast:15
    x = dpp_add<0x143>(x);  // row_bcast:31
    return x;
}

__global__ __launch_bounds__(256)
void fused_block_kernel(const float* __restrict__ state,   // (32,256,7)
                        const float* __restrict__ action,  // (32,256,2)
                        const float* __restrict__ Wk,      // (15,5)
                        const float* __restrict__ Wq,      // (15,9)
                        const float* __restrict__ Wv,      // (15,5)
                        const float* __restrict__ att_bias,// (5)
                        const float* __restrict__ Wscore,  // (1,5)
                        const float* __restrict__ bscore,  // (1)
                        const float* __restrict__ g1,
                        const float* __restrict__ beta1,
                        const float* __restrict__ W1,      // (75,15)
                        const float* __restrict__ bff1,    // (75)
                        const float* __restrict__ W2,      // (15,75)
                        const float* __restrict__ bff2,    // (15)
                        const float* __restrict__ g2,
                        const float* __restrict__ beta2,
                        float* __restrict__ out)           // (32,256,15)
{
    const int blk  = blockIdx.x;       // b*256 + i
    const int b    = blk >> 8;
    const int qi   = blk & 255;
    const int m    = threadIdx.x;      // neighbor slot (0..254 valid)
    const int lane = m & 63;
    const int wave = m >> 6;

    __shared__ __align__(16) float s_qb[16];   // q-proj + bias, padded
    __shared__ float s_red[4][NR];
    __shared__ float s_fin[NR];
    __shared__ float s_x[DD];
    __shared__ float s_h[HID];
    __shared__ float s_p2[HID];        // [5][15] partials of MLP2
    __shared__ float s_mv2[2];

    // ---- stage query projection (+ att_bias folded in)
    if (m < DD) {
        const float* st = state + ((size_t)b*TT + qi)*7;
        float acc = att_bias[m % KD];
        #pragma unroll
        for (int k = 0; k < 7; k++) acc += Wq[m*QD+k] * st[k];
        acc += Wq[m*QD+7] * action[((size_t)b*TT+qi)*2 + 0];
        acc += Wq[m*QD+8] * action[((size_t)b*TT+qi)*2 + 1];
        s_qb[m] = acc;
    }
    if (m == DD) s_qb[DD] = 0.0f;
    __syncthreads();

    // pull q+bias into registers via 4 vector LDS reads
    float qb[16];
    {
        float4 a0 = *(const float4*)&s_qb[0];
        float4 a1 = *(const float4*)&s_qb[4];
        float4 a2 = *(const float4*)&s_qb[8];
        float4 a3 = *(const float4*)&s_qb[12];
        qb[0]=a0.x; qb[1]=a0.y; qb[2]=a0.z; qb[3]=a0.w;
        qb[4]=a1.x; qb[5]=a1.y; qb[6]=a1.z; qb[7]=a1.w;
        qb[8]=a2.x; qb[9]=a2.y; qb[10]=a2.z; qb[11]=a2.w;
        qb[12]=a3.x; qb[13]=a3.y; qb[14]=a3.z; qb[15]=a3.w;
    }

    // ---- per-pair phase
    float red[NR];
    #pragma unroll
    for (int n = 0; n < NR; n++) red[n] = 0.0f;

    if (m < TM1) {
        const int jj = m + (m >= qi ? 1 : 0);
        const float* sti = state + ((size_t)b*TT + qi)*7;
        const float* stj = state + ((size_t)b*TT + jj)*7;
        const float d0 = stj[0]-sti[0];
        const float d1 = stj[1]-sti[1];
        const float d2 = stj[2]-sti[2];
        const float d3 = stj[3]-sti[3];
        const float ang = 1.5707963267948966f - stj[6];   // neighbor's heading
        float sn, cs;
        __sincosf(ang, &sn, &cs);
        const float xr0 = d0*cs - d1*sn;
        const float yr0 = d0*sn + d1*cs;
        const float xr1 = d2*cs - d3*sn;
        const float yr1 = d2*sn + d3*cs;
        const float s2   = xr0*xr0 + yr0*yr0;
        const float rinv = __builtin_amdgcn_rsqf(s2);
        const float r    = s2 * rinv;
        const float rt   = fast_rcp(1.0f + __expf(5.0f*r - 2.0f)); // sigmoid(1-5(r-0.2))
        const float kv0 = xr0*rinv, kv1 = yr0*rinv, kv2 = xr1, kv3 = yr1, kv4 = rt;

        const float sc_base = bscore[0];          // uniform -> scalar load
        #pragma unroll
        for (int h = 0; h < NH; h++) {
            float sc = sc_base;
            #pragma unroll
            for (int kk = 0; kk < KD; kk++) {
                const int d = h*KD + kk;
                // Wk read with compile-time-constant uniform index -> s_load
                float key = Wk[d*KD+0]*kv0 + Wk[d*KD+1]*kv1 + Wk[d*KD+2]*kv2
                          + Wk[d*KD+3]*kv3 + Wk[d*KD+4]*kv4;
                sc += fast_tanh(key + qb[d]) * Wscore[kk];
            }
            // |sc| <= ~2.7 -> safe without max-subtraction
            const float p = __expf(sc);
            red[h]           = p;
            red[NH+h*KD+0]   = p*kv0;
            red[NH+h*KD+1]   = p*kv1;
            red[NH+h*KD+2]   = p*kv2;
            red[NH+h*KD+3]   = p*kv3;
            red[NH+h*KD+4]   = p*kv4;
        }
    }

    // ---- block reduction: 3 denoms + 15 weighted-kv sums (Wv deferred)
    #pragma unroll
    for (int n = 0; n < NR; n++) red[n] = wave_sum63(red[n]);
    if (lane == 63) {
        #pragma unroll
        for (int n = 0; n < NR; n++) s_red[wave][n] = red[n];
    }
    __syncthreads();
    if (m < NR)
        s_fin[m] = s_red[0][m] + s_red[1][m] + s_red[2][m] + s_red[3][m];
    __syncthreads();

    // ---- epilogue: Wv projection + softmax normalize + LN1 (shuffle-based)
    if (m < 16) {
        float xm = 0.0f;
        if (m < DD) {
            const int h = m / KD;
            float acc = 0.0f;
            #pragma unroll
            for (int c = 0; c < KD; c++)
                acc += Wv[m*KD+c] * s_fin[NH + h*KD + c];
            xm = acc * fast_rcp(s_fin[h]);
        }
        float s1 = xm, sq = xm*xm;
        #pragma unroll
        for (int off = 8; off >= 1; off >>= 1) {
            s1 += __shfl_xor(s1, off, 16);
            sq += __shfl_xor(sq, off, 16);
        }
        const float mu   = s1 * (1.0f/DD);
        const float var  = sq * (1.0f/DD) - mu*mu;
        const float rstd = rsqrtf(var + 1e-5f);
        if (m < DD)
            s_x[m] = (xm - mu) * rstd * g1[m] + beta1[m];
    }
    __syncthreads();

    // ---- MLP layer 1: 75 hidden units, one per thread
    if (m < HID) {
        float acc = bff1[m];
        #pragma unroll
        for (int k = 0; k < DD; k++) acc += W1[m*DD+k] * s_x[k];
        s_h[m] = fmaxf(acc, 0.0f);
    }
    __syncthreads();

    // ---- MLP layer 2: split over 75 threads = 5 j-chunks x 15 outputs
    if (m < HID) {
        const int c = m / DD;     // j-chunk
        const int d = m % DD;     // output dim
        float acc = 0.0f;
        #pragma unroll
        for (int k = 0; k < DD; k++)
            acc += W2[d*HID + c*DD + k] * s_h[c*DD + k];
        s_p2[m] = acc;
    }
    __syncthreads();

    // ---- residual + LN2 + store (shuffle-based)
    if (m < 16) {
        float x2 = 0.0f;
        if (m < DD)
            x2 = s_x[m] + bff2[m] + s_p2[m] + s_p2[DD+m] + s_p2[2*DD+m]
               + s_p2[3*DD+m] + s_p2[4*DD+m];
        float s1 = x2, sq = x2*x2;
        #pragma unroll
        for (int off = 8; off >= 1; off >>= 1) {
            s1 += __shfl_xor(s1, off, 16);
            sq += __shfl_xor(sq, off, 16);
        }
        const float mu   = s1 * (1.0f/DD);
        const float var  = sq * (1.0f/DD) - mu*mu;
        const float rstd = rsqrtf(var + 1e-5f);
        if (m < DD)
            out[(size_t)blk*DD + m] = (x2 - mu) * rstd * g2[m] + beta2[m];
    }
    (void)s_mv2;
}

extern "C" void kernel_launch(void* const* d_in, const int* in_sizes, int n_in,
                              void* d_out, int out_size, void* d_ws, size_t ws_size,
                              hipStream_t stream) {
    const float* state    = (const float*)d_in[0];
    const float* action   = (const float*)d_in[1];
    const float* Wk       = (const float*)d_in[2];
    const float* Wq       = (const float*)d_in[3];
    const float* Wv       = (const float*)d_in[4];
    const float* att_bias = (const float*)d_in[5];
    const float* Wscore   = (const float*)d_in[6];
    const float* bscore   = (const float*)d_in[7];
    const float* g1       = (const float*)d_in[8];
    const float* beta1    = (const float*)d_in[9];
    const float* W1       = (const float*)d_in[10];
    const float* bff1     = (const float*)d_in[11];
    const float* W2       = (const float*)d_in[12];
    const float* bff2     = (const float*)d_in[13];
    const float* g2       = (const float*)d_in[14];
    const float* beta2    = (const float*)d_in[15];
    float* out = (float*)d_out;

    dim3 grid(32 * 256);
    dim3 block(256);
    fused_block_kernel<<<grid, block, 0, stream>>>(
        state, action, Wk, Wq, Wv, att_bias, Wscore, bscore,
        g1, beta1, W1, bff1, W2, bff2, g2, beta2, out);
}

// Round 3
// 29.658 us; speedup vs baseline: 2.3133x; 1.1950x over previous
//
#include <hip/hip_runtime.h>
#include <math.h>

#define TT   256
#define TM1  255
#define QD   9
#define KD   5
#define NH   3
#define DD   15   // NH*KD
#define HID  75   // 5*DD
#define NR   18   // NH + DD reduce values

__device__ __forceinline__ float fast_rcp(float x) {
    return __builtin_amdgcn_rcpf(x);   // v_rcp_f32
}

template<int CTRL>
__device__ __forceinline__ float dpp_add(float x) {
    int y = __builtin_amdgcn_update_dpp(0, __float_as_int(x), CTRL, 0xf, 0xf, true);
    return x + __int_as_float(y);
}

// full-rate VALU wave64 sum; result valid in lane 63
__device__ __forceinline__ float wave_sum63(float x) {
    x = dpp_add<0x111>(x);  // row_shr:1
    x = dpp_add<0x112>(x);  // row_shr:2
    x = dpp_add<0x114>(x);  // row_shr:4
    x = dpp_add<0x118>(x);  // row_shr:8
    x = dpp_add<0x142>(x);  // row_bcast:15
    x = dpp_add<0x143>(x);  // row_bcast:31
    return x;
}

__device__ __forceinline__ float bcast(float x, int l) {
    return __int_as_float(__builtin_amdgcn_readlane(__float_as_int(x), l));
}

__global__ __launch_bounds__(64)
void fused_block_kernel(const float* __restrict__ state,   // (32,256,7)
                        const float* __restrict__ action,  // (32,256,2)
                        const float* __restrict__ Wk,      // (15,5)
                        const float* __restrict__ Wq,      // (15,9)
                        const float* __restrict__ Wv,      // (15,5)
                        const float* __restrict__ att_bias,// (5)
                        const float* __restrict__ Wscore,  // (1,5)
                        const float* __restrict__ bscore,  // (1)
                        const float* __restrict__ g1,
                        const float* __restrict__ beta1,
                        const float* __restrict__ W1,      // (75,15)
                        const float* __restrict__ bff1,    // (75)
                        const float* __restrict__ W2,      // (15,75)
                        const float* __restrict__ bff2,    // (15)
                        const float* __restrict__ g2,
                        const float* __restrict__ beta2,
                        float* __restrict__ out)           // (32,256,15)
{
    const int blk = blockIdx.x;        // b*256 + i
    const int b   = blk >> 8;
    const int qi  = blk & 255;
    const int m   = threadIdx.x;       // 0..63; handles neighbors m, m+64, m+128, m+192

    __shared__ __align__(16) float s_h[76];   // MLP hidden (padded, s_h[75]=0)

    const float* sti = state + ((size_t)b*TT + qi)*7;
    const float si0 = sti[0], si1 = sti[1], si2 = sti[2], si3 = sti[3];

    // ---- query projection (+att_bias folded) in lanes 0..14, then SGPR broadcast
    float qv = 0.0f;
    if (m < DD) {
        float acc = att_bias[m % KD];
        #pragma unroll
        for (int k = 0; k < 7; k++) acc = fmaf(Wq[m*QD+k], sti[k], acc);
        acc = fmaf(Wq[m*QD+7], action[((size_t)b*TT+qi)*2 + 0], acc);
        acc = fmaf(Wq[m*QD+8], action[((size_t)b*TT+qi)*2 + 1], acc);
        qv = acc;
    }
    float qb[DD];
    #pragma unroll
    for (int d = 0; d < DD; d++) qb[d] = bcast(qv, d);

    // score constants: sc = C - 2*sum_kk wsc_kk/(e_kk+1),  C = bscore + sum wsc
    float wsc2[KD];
    float C = bscore[0];
    #pragma unroll
    for (int kk = 0; kk < KD; kk++) { float w = Wscore[kk]; wsc2[kk] = -2.0f*w; C += w; }

    // ---- per-pair phase: 4 neighbors per thread, accumulate in registers
    float red[NR];
    #pragma unroll
    for (int n = 0; n < NR; n++) red[n] = 0.0f;

    #pragma unroll
    for (int pp = 0; pp < 4; pp++) {
        const int mm = m + pp*64;
        if (mm < TM1) {
            const int jj = mm + (mm >= qi ? 1 : 0);
            const float* stj = state + ((size_t)b*TT + jj)*7;
            const float d0 = stj[0]-si0, d1 = stj[1]-si1;
            const float d2 = stj[2]-si2, d3 = stj[3]-si3;
            // ref rotates by ang = pi/2 - theta_j: cos(ang)=sin(theta), sin(ang)=cos(theta)
            float cs, sn;                    // cs = sin(theta_j), sn = cos(theta_j)
            __sincosf(stj[6], &cs, &sn);
            const float xr0 = d0*cs - d1*sn, yr0 = d0*sn + d1*cs;
            const float xr1 = d2*cs - d3*sn, yr1 = d2*sn + d3*cs;
            const float s2   = xr0*xr0 + yr0*yr0;
            const float rinv = __builtin_amdgcn_rsqf(s2);
            const float r    = s2 * rinv;
            const float rt   = fast_rcp(1.0f + __expf(fmaf(5.0f, r, -2.0f))); // sigmoid(1-5(r-0.2))
            const float kv0 = xr0*rinv, kv1 = yr0*rinv;   // kv2=xr1, kv3=yr1, kv4=rt

            #pragma unroll
            for (int h = 0; h < NH; h++) {
                float sc = C;
                #pragma unroll
                for (int kk = 0; kk < KD; kk++) {
                    const int d = h*KD + kk;
                    float a = qb[d];
                    a = fmaf(Wk[d*KD+0], kv0, a);
                    a = fmaf(Wk[d*KD+1], kv1, a);
                    a = fmaf(Wk[d*KD+2], xr1, a);
                    a = fmaf(Wk[d*KD+3], yr1, a);
                    a = fmaf(Wk[d*KD+4], rt , a);
                    // tanh folded: wsc*tanh(a) = wsc - 2*wsc/(exp(2a)+1)
                    sc = fmaf(wsc2[kk], fast_rcp(__expf(a + a) + 1.0f), sc);
                }
                // |sc| bounded (~2.7) -> safe without max-subtraction
                const float p = __expf(sc);
                red[h] += p;
                red[NH+h*KD+0] = fmaf(p, kv0, red[NH+h*KD+0]);
                red[NH+h*KD+1] = fmaf(p, kv1, red[NH+h*KD+1]);
                red[NH+h*KD+2] = fmaf(p, xr1, red[NH+h*KD+2]);
                red[NH+h*KD+3] = fmaf(p, yr1, red[NH+h*KD+3]);
                red[NH+h*KD+4] = fmaf(p, rt , red[NH+h*KD+4]);
            }
        }
    }

    // ---- single wave reduction + SGPR broadcast of the 18 totals
    #pragma unroll
    for (int n = 0; n < NR; n++) red[n] = wave_sum63(red[n]);
    float fin[NR];
    #pragma unroll
    for (int n = 0; n < NR; n++) fin[n] = bcast(red[n], 63);

    // ---- Wv projection (deferred, linear) + softmax normalize (lanes 0..14)
    float xm = 0.0f;
    if (m < DD) {
        const int h = m / KD;
        float acc = 0.0f;
        #pragma unroll
        for (int c = 0; c < KD; c++) acc = fmaf(Wv[m*KD+c], fin[NH+h*KD+c], acc);
        xm = acc * fast_rcp(fin[h]);
    }

    // ---- LN1 across lanes 0..15 (lane 15 contributes 0)
    float s1 = xm, sq = xm*xm;
    #pragma unroll
    for (int off = 8; off >= 1; off >>= 1) {
        s1 += __shfl_xor(s1, off, 16);
        sq += __shfl_xor(sq, off, 16);
    }
    const float mu1   = s1 * (1.0f/DD);
    const float rstd1 = rsqrtf(sq * (1.0f/DD) - mu1*mu1 + 1e-5f);
    float xln = 0.0f;
    if (m < DD) xln = (xm - mu1) * rstd1 * g1[m] + beta1[m];

    // broadcast LN1 output to uniform scalars for the MLP
    float xs[DD];
    #pragma unroll
    for (int d = 0; d < DD; d++) xs[d] = bcast(xln, d);

    // ---- MLP layer 1: 75 hidden units over 64 lanes (lanes 0..10 do two)
    {
        float h0 = bff1[m];
        #pragma unroll
        for (int k = 0; k < DD; k++) h0 = fmaf(W1[m*DD+k], xs[k], h0);
        s_h[m] = fmaxf(h0, 0.0f);
        if (m < HID-64) {
            float h1 = bff1[m+64];
            #pragma unroll
            for (int k = 0; k < DD; k++) h1 = fmaf(W1[(m+64)*DD+k], xs[k], h1);
            s_h[m+64] = fmaxf(h1, 0.0f);
        }
        if (m == 11) s_h[75] = 0.0f;
    }
    __syncthreads();

    // ---- MLP layer 2 + residual (lanes 0..14), LN2, store
    float x2 = 0.0f;
    if (m < DD) {
        float acc = bff2[m];
        const float4* hv = (const float4*)s_h;
        #pragma unroll
        for (int c = 0; c < 18; c++) {
            const float4 hh = hv[c];
            acc = fmaf(W2[m*HID + 4*c+0], hh.x, acc);
            acc = fmaf(W2[m*HID + 4*c+1], hh.y, acc);
            acc = fmaf(W2[m*HID + 4*c+2], hh.z, acc);
            acc = fmaf(W2[m*HID + 4*c+3], hh.w, acc);
        }
        acc = fmaf(W2[m*HID+72], s_h[72], acc);
        acc = fmaf(W2[m*HID+73], s_h[73], acc);
        acc = fmaf(W2[m*HID+74], s_h[74], acc);
        x2 = xln + acc;               // residual uses post-LN1 x
    }
    float t1 = x2, t2 = x2*x2;
    #pragma unroll
    for (int off = 8; off >= 1; off >>= 1) {
        t1 += __shfl_xor(t1, off, 16);
        t2 += __shfl_xor(t2, off, 16);
    }
    const float mu2   = t1 * (1.0f/DD);
    const float rstd2 = rsqrtf(t2 * (1.0f/DD) - mu2*mu2 + 1e-5f);
    if (m < DD)
        out[(size_t)blk*DD + m] = (x2 - mu2) * rstd2 * g2[m] + beta2[m];
}

extern "C" void kernel_launch(void* const* d_in, const int* in_sizes, int n_in,
                              void* d_out, int out_size, void* d_ws, size_t ws_size,
                              hipStream_t stream) {
    const float* state    = (const float*)d_in[0];
    const float* action   = (const float*)d_in[1];
    const float* Wk       = (const float*)d_in[2];
    const float* Wq       = (const float*)d_in[3];
    const float* Wv       = (const float*)d_in[4];
    const float* att_bias = (const float*)d_in[5];
    const float* Wscore   = (const float*)d_in[6];
    const float* bscore   = (const float*)d_in[7];
    const float* g1       = (const float*)d_in[8];
    const float* beta1    = (const float*)d_in[9];
    const float* W1       = (const float*)d_in[10];
    const float* bff1     = (const float*)d_in[11];
    const float* W2       = (const float*)d_in[12];
    const float* bff2     = (const float*)d_in[13];
    const float* g2       = (const float*)d_in[14];
    const float* beta2    = (const float*)d_in[15];
    float* out = (float*)d_out;

    dim3 grid(32 * 256);
    dim3 block(64);
    fused_block_kernel<<<grid, block, 0, stream>>>(
        state, action, Wk, Wq, Wv, att_bias, Wscore, bscore,
        g1, beta1, W1, bff1, W2, bff2, g2, beta2, out);
}